// Round 5
// baseline (427.405 us; speedup 1.0000x reference)
//
#include <hip/hip_runtime.h>

typedef unsigned short u16;
typedef unsigned int u32;
typedef __attribute__((ext_vector_type(8))) short short8;
typedef __attribute__((ext_vector_type(8))) __bf16 bf16x8;
typedef __attribute__((ext_vector_type(4))) float f32x4;

// ---------- bf16 <-> f32 (raw, RNE) ----------
__device__ __forceinline__ float bf2f(u16 u) { return __uint_as_float(((u32)u) << 16); }
__device__ __forceinline__ u16 f2bf(float f) {
  u32 u = __float_as_uint(f);
  u = (u + 0x7fffu + ((u >> 16) & 1u)) >> 16;
  return (u16)u;
}

// ---------- MFMA wrapper: tolerate either short8 or bf16x8 builtin signature ----------
template <typename V>
__device__ __forceinline__ auto mfma_try(V a, V b, f32x4 c, int)
    -> decltype(__builtin_amdgcn_mfma_f32_16x16x32_bf16(a, b, c, 0, 0, 0)) {
  return __builtin_amdgcn_mfma_f32_16x16x32_bf16(a, b, c, 0, 0, 0);
}
template <typename V>
__device__ __forceinline__ f32x4 mfma_try(V a, V b, f32x4 c, long) {
  return __builtin_amdgcn_mfma_f32_16x16x32_bf16(
      __builtin_bit_cast(bf16x8, a), __builtin_bit_cast(bf16x8, b), c, 0, 0, 0);
}
__device__ __forceinline__ f32x4 MFMA(short8 a, short8 b, f32x4 c) {
  return mfma_try(a, b, c, 0);
}

// ---------- async global->LDS, 16B per lane (GEMM only) ----------
#define GLOAD16(gsrc, ldst)                                                  \
  __builtin_amdgcn_global_load_lds(                                          \
      (const __attribute__((address_space(1))) void*)(gsrc),                 \
      (__attribute__((address_space(3))) void*)(ldst), 16, 0, 0)

// Problem constants
#define SQ 2048
#define NH 16
#define DH 64
#define DMODEL 1024

// =====================================================================
// dtype detector: writes flag=1 if inputs are float32, 0 if bf16.
// Samples u16s at EVEN indices of query. bf16 data: every sample is a
// N(0,1)-ish bf16 -> exponent field in [96,143] (~100% accept). f32 data:
// even u16s are low mantissa halves -> ~uniform -> ~19% accept.
// =====================================================================
__global__ void detect_dtype(const u16* __restrict__ q, int* __restrict__ flag) {
  __shared__ int cnt;
  if (threadIdx.x == 0) cnt = 0;
  __syncthreads();
  const int k = threadIdx.x * 16384 + 128;   // < 4.19M, even index 2k < 8.39M u16s
  const u16 u = q[2 * k];
  const int e = (u >> 7) & 0xFF;
  if (e >= 96 && e <= 143) atomicAdd(&cnt, 1);
  __syncthreads();
  if (threadIdx.x == 0) *flag = (cnt < 128) ? 1 : 0;
}

// ---------- conversion helpers ----------
__device__ __forceinline__ short8 cvt8_f32(const float* s) {
  f32x4 a = *(const f32x4*)s;
  f32x4 b = *(const f32x4*)(s + 4);
  short8 o;
#pragma unroll
  for (int j = 0; j < 4; ++j) o[j] = (short)f2bf(a[j]);
#pragma unroll
  for (int j = 0; j < 4; ++j) o[4 + j] = (short)f2bf(b[j]);
  return o;
}

// canonicalize one tensor to bf16 (n8 = n/8 vec items)
__global__ void cvt_tensor(const void* __restrict__ src, u16* __restrict__ dst,
                           int n8, const int* __restrict__ flag) {
  const bool isf32 = (*flag != 0);
  int i = blockIdx.x * blockDim.x + threadIdx.x;
  const int stride = gridDim.x * blockDim.x;
  if (isf32) {
    const float* s = (const float*)src;
    for (; i < n8; i += stride) *(short8*)(dst + i * 8) = cvt8_f32(s + i * 8);
  } else {
    const short8* s = (const short8*)src;
    for (; i < n8; i += stride) *(short8*)(dst + i * 8) = s[i];
  }
}

// 4 weight tensors (each 2^20 elems) -> dst 4 contiguous slabs
__global__ void cvt_w4(const void* s0, const void* s1, const void* s2, const void* s3,
                       u16* __restrict__ dst, const int* __restrict__ flag) {
  const bool isf32 = (*flag != 0);
  int i = blockIdx.x * blockDim.x + threadIdx.x;
  const int stride = gridDim.x * blockDim.x;
  for (; i < (1 << 19); i += stride) {
    const int seg = i >> 17, off = i & ((1 << 17) - 1);
    const void* s = (seg == 0) ? s0 : (seg == 1) ? s1 : (seg == 2) ? s2 : s3;
    u16* d = dst + ((long)seg << 20) + (long)off * 8;
    if (isf32) *(short8*)d = cvt8_f32((const float*)s + off * 8);
    else *(short8*)d = *((const short8*)s + off);
  }
}

// 4 bias tensors (each 1024 elems) -> dst 4 contiguous slabs
__global__ void cvt_b4(const void* s0, const void* s1, const void* s2, const void* s3,
                       u16* __restrict__ dst, const int* __restrict__ flag) {
  const bool isf32 = (*flag != 0);
  int i = blockIdx.x * blockDim.x + threadIdx.x;
  if (i >= 512) return;
  const int seg = i >> 7, off = i & 127;
  const void* s = (seg == 0) ? s0 : (seg == 1) ? s1 : (seg == 2) ? s2 : s3;
  u16* d = dst + seg * 1024 + off * 8;
  if (isf32) *(short8*)d = cvt8_f32((const float*)s + off * 8);
  else *(short8*)d = *((const short8*)s + off);
}

// =====================================================================
// GEMM: C[M][N] = A[M][K] * W[N][K]^T + bias[N]   (bf16 in)
// MODE 0: C row-major [M][N], dtype per flag (f32 or bf16)
// MODE 1: heads layout  [B][H][S][Dh]  (q, k)     bf16
// MODE 2: transposed    [B*H][Dh][S]   (vT)       bf16
// 128x128 tile, BK=32, 256 threads (4 waves, each 64x64)  [m97 structure]
// =====================================================================
template <int MODE>
__global__ __launch_bounds__(256, 2) void gemm_bt(
    const u16* __restrict__ A, const u16* __restrict__ W,
    const u16* __restrict__ bias, void* __restrict__ Cv,
    const int* __restrict__ flag, int M, int N, int K) {
  __shared__ __align__(16) u16 As[128 * 32];
  __shared__ __align__(16) u16 Bs[128 * 32];
  const int tid = threadIdx.x;
  const int lane = tid & 63;
  const int wv = tid >> 6;
  const int wr = wv >> 1, wc = wv & 1;
  const bool isf32 = (MODE == 0) && (*flag != 0);

  const int nwg = gridDim.x;
  const int cpx = nwg >> 3;
  const int bid = (blockIdx.x % 8) * cpx + (blockIdx.x >> 3);

  const int tiles_n = N >> 7;
  const int tm = bid / tiles_n, tn = bid % tiles_n;
  const int m0 = tm << 7, n0 = tn << 7;

  f32x4 acc[4][4];
#pragma unroll
  for (int i = 0; i < 4; ++i)
#pragma unroll
    for (int j = 0; j < 4; ++j)
#pragma unroll
      for (int r = 0; r < 4; ++r) acc[i][j][r] = 0.f;

  const int srow = tid >> 2;
  const int skk = (tid & 3) * 8;
  const u16* a0 = A + (long)(m0 + srow) * K + skk;
  const u16* a1 = A + (long)(m0 + 64 + srow) * K + skk;
  const u16* b0 = W + (long)(n0 + srow) * K + skk;
  const u16* b1 = W + (long)(n0 + 64 + srow) * K + skk;
  u16* lA0 = &As[tid * 8];
  u16* lA1 = &As[(256 + tid) * 8];
  u16* lB0 = &Bs[tid * 8];
  u16* lB1 = &Bs[(256 + tid) * 8];

  const int rk = 8 * (lane >> 4);
  const int rrow = lane & 15;
  const int r0 = (lane >> 4) * 4;

  for (int k0 = 0; k0 < K; k0 += 32) {
    GLOAD16(a0 + k0, lA0);
    GLOAD16(a1 + k0, lA1);
    GLOAD16(b0 + k0, lB0);
    GLOAD16(b1 + k0, lB1);
    asm volatile("s_waitcnt vmcnt(0)" ::: "memory");
    __syncthreads();
    short8 af[4], bf[4];
#pragma unroll
    for (int mi = 0; mi < 4; ++mi)
      af[mi] = *(const short8*)&As[(wr * 64 + mi * 16 + rrow) * 32 + rk];
#pragma unroll
    for (int ni = 0; ni < 4; ++ni)
      bf[ni] = *(const short8*)&Bs[(wc * 64 + ni * 16 + rrow) * 32 + rk];
#pragma unroll
    for (int mi = 0; mi < 4; ++mi)
#pragma unroll
      for (int ni = 0; ni < 4; ++ni)
        acc[mi][ni] = MFMA(af[mi], bf[ni], acc[mi][ni]);
    __syncthreads();
  }

#pragma unroll
  for (int ni = 0; ni < 4; ++ni) {
    const int col = n0 + wc * 64 + ni * 16 + rrow;
    const float bv = bf2f(bias[col]);
#pragma unroll
    for (int mi = 0; mi < 4; ++mi) {
#pragma unroll
      for (int r = 0; r < 4; ++r) {
        const int row = m0 + wr * 64 + mi * 16 + r0 + r;
        const float v = acc[mi][ni][r] + bv;
        if (MODE == 0) {
          const long idx = (long)row * N + col;
          if (isf32) ((float*)Cv)[idx] = v;
          else ((u16*)Cv)[idx] = f2bf(v);
        } else if (MODE == 1) {
          const int b = row >> 11, s = row & 2047, h = col >> 6, dh = col & 63;
          ((u16*)Cv)[(((long)(b * NH + h) * SQ) + s) * DH + dh] = f2bf(v);
        } else {
          const int b = row >> 11, s = row & 2047, h = col >> 6, dh = col & 63;
          ((u16*)Cv)[(((long)(b * NH + h) * DH) + dh) * SQ + s] = f2bf(v);
        }
      }
    }
  }
}

// =====================================================================
// Flash attention (hardened): q,k in [BH][S][64], vT in [BH][64][S],
// out ctx [B][S][H][64].  grid (S/128, BH), 256 threads = 4 waves.
// =====================================================================
#define LSTR 72

__global__ __launch_bounds__(256, 2) void attn_kernel(
    const u16* __restrict__ q, const u16* __restrict__ k,
    const u16* __restrict__ vT, const int* __restrict__ mask,
    u16* __restrict__ ctx) {
  __shared__ __align__(16) u16 Ks[64 * LSTR];
  __shared__ __align__(16) u16 Vs[64 * LSTR];
  __shared__ __align__(16) u16 Ps[4][32 * LSTR];
  __shared__ int Ms[64];

  const int tid = threadIdx.x, lane = tid & 63, wv = tid >> 6;
  const int bh = blockIdx.y, b = bh >> 4, h = bh & 15;
  const int q0 = blockIdx.x * 128 + wv * 32;
  const u16* qb = q + (long)bh * SQ * DH;
  const u16* kb = k + (long)bh * SQ * DH;
  const u16* vb = vT + (long)bh * DH * SQ;
  const int rk = 8 * (lane >> 4), rrow = lane & 15, r0 = (lane >> 4) * 4;

  short8 aq[2][2];
#pragma unroll
  for (int mi = 0; mi < 2; ++mi)
#pragma unroll
    for (int ks = 0; ks < 2; ++ks)
      aq[mi][ks] = *(const short8*)&qb[(long)(q0 + mi * 16 + rrow) * DH + ks * 32 + rk];

  f32x4 oacc[2][4];
  f32x4 mrow[2], lrow[2];
#pragma unroll
  for (int mi = 0; mi < 2; ++mi) {
#pragma unroll
    for (int r = 0; r < 4; ++r) { mrow[mi][r] = -1.0e9f; lrow[mi][r] = 0.f; }
#pragma unroll
    for (int nf = 0; nf < 4; ++nf)
#pragma unroll
      for (int r = 0; r < 4; ++r) oacc[mi][nf][r] = 0.f;
  }

  const int stg_r = tid >> 3;
  const int stg_c = (tid & 7) * 8;

  for (int t0 = 0; t0 < SQ; t0 += 64) {
    const short8 kv0 = *(const short8*)&kb[(long)(t0 + stg_r) * DH + stg_c];
    const short8 kv1 = *(const short8*)&kb[(long)(t0 + 32 + stg_r) * DH + stg_c];
    const short8 vv0 = *(const short8*)&vb[(long)stg_r * SQ + t0 + stg_c];
    const short8 vv1 = *(const short8*)&vb[(long)(32 + stg_r) * SQ + t0 + stg_c];
    int mv = 0;
    if (tid < 64) mv = mask[b * SQ + t0 + tid];

    __syncthreads();
    *(short8*)&Ks[stg_r * LSTR + stg_c] = kv0;
    *(short8*)&Ks[(32 + stg_r) * LSTR + stg_c] = kv1;
    *(short8*)&Vs[stg_r * LSTR + stg_c] = vv0;
    *(short8*)&Vs[(32 + stg_r) * LSTR + stg_c] = vv1;
    if (tid < 64) Ms[tid] = mv;
    __syncthreads();

    f32x4 sacc[2][4];
#pragma unroll
    for (int mi = 0; mi < 2; ++mi)
#pragma unroll
      for (int ni = 0; ni < 4; ++ni)
#pragma unroll
        for (int r = 0; r < 4; ++r) sacc[mi][ni][r] = 0.f;
#pragma unroll
    for (int ks = 0; ks < 2; ++ks) {
#pragma unroll
      for (int ni = 0; ni < 4; ++ni) {
        const short8 bk = *(const short8*)&Ks[(ni * 16 + rrow) * LSTR + ks * 32 + rk];
#pragma unroll
        for (int mi = 0; mi < 2; ++mi)
          sacc[mi][ni] = MFMA(aq[mi][ks], bk, sacc[mi][ni]);
      }
    }

#pragma unroll
    for (int ni = 0; ni < 4; ++ni) {
      const bool keep = Ms[ni * 16 + rrow] != 0;
#pragma unroll
      for (int mi = 0; mi < 2; ++mi)
#pragma unroll
        for (int r = 0; r < 4; ++r)
          sacc[mi][ni][r] = keep ? sacc[mi][ni][r] * 0.125f : -1.0e9f;
    }

#pragma unroll
    for (int mi = 0; mi < 2; ++mi) {
      f32x4 tmax = sacc[mi][0];
#pragma unroll
      for (int ni = 1; ni < 4; ++ni)
#pragma unroll
        for (int r = 0; r < 4; ++r) tmax[r] = fmaxf(tmax[r], sacc[mi][ni][r]);
#pragma unroll
      for (int d = 1; d < 16; d <<= 1)
#pragma unroll
        for (int r = 0; r < 4; ++r) tmax[r] = fmaxf(tmax[r], __shfl_xor(tmax[r], d));

      f32x4 mnew, sc;
#pragma unroll
      for (int r = 0; r < 4; ++r) {
        mnew[r] = fmaxf(mrow[mi][r], tmax[r]);
        sc[r] = __expf(mrow[mi][r] - mnew[r]);
      }
      f32x4 tsum;
#pragma unroll
      for (int r = 0; r < 4; ++r) tsum[r] = 0.f;
#pragma unroll
      for (int ni = 0; ni < 4; ++ni)
#pragma unroll
        for (int r = 0; r < 4; ++r) {
          const float p = __expf(sacc[mi][ni][r] - mnew[r]);
          sacc[mi][ni][r] = p;
          tsum[r] += p;
        }
#pragma unroll
      for (int d = 1; d < 16; d <<= 1)
#pragma unroll
        for (int r = 0; r < 4; ++r) tsum[r] += __shfl_xor(tsum[r], d);
#pragma unroll
      for (int r = 0; r < 4; ++r) {
        lrow[mi][r] = lrow[mi][r] * sc[r] + tsum[r];
        mrow[mi][r] = mnew[r];
      }
#pragma unroll
      for (int nf = 0; nf < 4; ++nf)
#pragma unroll
        for (int r = 0; r < 4; ++r) oacc[mi][nf][r] *= sc[r];

#pragma unroll
      for (int ni = 0; ni < 4; ++ni)
#pragma unroll
        for (int r = 0; r < 4; ++r)
          Ps[wv][(mi * 16 + r0 + r) * LSTR + ni * 16 + rrow] = f2bf(sacc[mi][ni][r]);
    }

    __syncthreads();

#pragma unroll
    for (int ks2 = 0; ks2 < 2; ++ks2) {
      short8 pa[2];
#pragma unroll
      for (int mi = 0; mi < 2; ++mi)
        pa[mi] = *(const short8*)&Ps[wv][(mi * 16 + rrow) * LSTR + ks2 * 32 + rk];
#pragma unroll
      for (int nf = 0; nf < 4; ++nf) {
        const short8 bvv = *(const short8*)&Vs[(nf * 16 + rrow) * LSTR + ks2 * 32 + rk];
#pragma unroll
        for (int mi = 0; mi < 2; ++mi)
          oacc[mi][nf] = MFMA(pa[mi], bvv, oacc[mi][nf]);
      }
    }
  }

#pragma unroll
  for (int mi = 0; mi < 2; ++mi)
#pragma unroll
    for (int nf = 0; nf < 4; ++nf)
#pragma unroll
      for (int r = 0; r < 4; ++r) {
        const int s = q0 + mi * 16 + r0 + r;
        const int dh = nf * 16 + rrow;
        const float v = oacc[mi][nf][r] / lrow[mi][r];
        ctx[(((long)(b * SQ + s)) * NH + h) * DH + dh] = f2bf(v);
      }
}

// =====================================================================
extern "C" void kernel_launch(void* const* d_in, const int* in_sizes, int n_in,
                              void* d_out, int out_size, void* d_ws, size_t ws_size,
                              hipStream_t stream) {
  const void* query = d_in[0];
  const int* mask = (const int*)d_in[1];
  const void* Wq = d_in[2];
  const void* bq = d_in[3];
  const void* Wk = d_in[4];
  const void* bk = d_in[5];
  const void* Wv = d_in[6];
  const void* bv = d_in[7];
  const void* Wo = d_in[8];
  const void* bo = d_in[9];

  // ws layout (bytes)
  char* w = (char*)d_ws;
  int* flag = (int*)w;
  u16* qc = (u16*)(w + 256);                 // 8.39M u16
  u16* Wc = qc + (long)8388608;              // 4 x 1M u16
  u16* bc = Wc + (long)4 * 1048576;          // 4 x 1024 u16
  u16* qb = bc + 4096;                       // heads Q
  u16* kb = qb + (long)8388608;              // heads K
  u16* vT = kb + (long)8388608;              // V transposed
  u16* ctx = vT + (long)8388608;             // attention output

  dim3 blk(256);

  detect_dtype<<<1, 256, 0, stream>>>((const u16*)query, flag);
  cvt_tensor<<<2048, 256, 0, stream>>>(query, qc, 8388608 / 8, flag);
  cvt_w4<<<2048, 256, 0, stream>>>(Wq, Wk, Wv, Wo, Wc, flag);
  cvt_b4<<<2, 256, 0, stream>>>(bq, bk, bv, bo, bc, flag);

  const int M = 4 * SQ;  // 8192
  dim3 gemm_grid((M / 128) * (DMODEL / 128));  // 512

  gemm_bt<1><<<gemm_grid, blk, 0, stream>>>(qc, Wc, bc, (void*)qb, flag, M, DMODEL, DMODEL);
  gemm_bt<1><<<gemm_grid, blk, 0, stream>>>(qc, Wc + 1048576, bc + 1024, (void*)kb, flag, M, DMODEL, DMODEL);
  gemm_bt<2><<<gemm_grid, blk, 0, stream>>>(qc, Wc + 2 * 1048576, bc + 2048, (void*)vT, flag, M, DMODEL, DMODEL);

  dim3 attn_grid(SQ / 128, 64);
  attn_kernel<<<attn_grid, blk, 0, stream>>>(qb, kb, vT, mask, ctx);

  gemm_bt<0><<<gemm_grid, blk, 0, stream>>>(ctx, Wc + 3 * 1048576, bc + 3072, d_out, flag, M, DMODEL, DMODEL);
}

// Round 6
// 345.429 us; speedup vs baseline: 1.2373x; 1.2373x over previous
//
#include <hip/hip_runtime.h>

typedef unsigned short u16;
typedef unsigned int u32;
typedef __attribute__((ext_vector_type(8))) short short8;
typedef __attribute__((ext_vector_type(8))) __bf16 bf16x8;
typedef __attribute__((ext_vector_type(4))) float f32x4;
typedef __attribute__((ext_vector_type(2))) u32 u32x2;

// ---------- bf16 <-> f32 (raw, RNE) ----------
__device__ __forceinline__ float bf2f(u16 u) { return __uint_as_float(((u32)u) << 16); }
__device__ __forceinline__ u16 f2bf(float f) {
  u32 u = __float_as_uint(f);
  u = (u + 0x7fffu + ((u >> 16) & 1u)) >> 16;
  return (u16)u;
}

// ---------- fast 2^x ----------
__device__ __forceinline__ float EXP2(float x) {
#if __has_builtin(__builtin_amdgcn_exp2f)
  return __builtin_amdgcn_exp2f(x);
#else
  return exp2f(x);
#endif
}

// ---------- packed f32x2 -> bf16x2 (RNE), gfx950 v_cvt_pk_bf16_f32 ----------
__device__ __forceinline__ u32 CVTPK(float lo, float hi) {
  u32 r;
  asm("v_cvt_pk_bf16_f32 %0, %1, %2" : "=v"(r) : "v"(lo), "v"(hi));
  return r;
}

// ---------- MFMA wrapper: tolerate either short8 or bf16x8 builtin signature ----------
template <typename V>
__device__ __forceinline__ auto mfma_try(V a, V b, f32x4 c, int)
    -> decltype(__builtin_amdgcn_mfma_f32_16x16x32_bf16(a, b, c, 0, 0, 0)) {
  return __builtin_amdgcn_mfma_f32_16x16x32_bf16(a, b, c, 0, 0, 0);
}
template <typename V>
__device__ __forceinline__ f32x4 mfma_try(V a, V b, f32x4 c, long) {
  return __builtin_amdgcn_mfma_f32_16x16x32_bf16(
      __builtin_bit_cast(bf16x8, a), __builtin_bit_cast(bf16x8, b), c, 0, 0, 0);
}
__device__ __forceinline__ f32x4 MFMA(short8 a, short8 b, f32x4 c) {
  return mfma_try(a, b, c, 0);
}

// ---------- async global->LDS, 16B per lane (GEMM only) ----------
#define GLOAD16(gsrc, ldst)                                                  \
  __builtin_amdgcn_global_load_lds(                                          \
      (const __attribute__((address_space(1))) void*)(gsrc),                 \
      (__attribute__((address_space(3))) void*)(ldst), 16, 0, 0)

// Problem constants
#define SQ 2048
#define NH 16
#define DH 64
#define DMODEL 1024

// =====================================================================
// dtype detector: writes flag=1 if inputs are float32, 0 if bf16.
// =====================================================================
__global__ void detect_dtype(const u16* __restrict__ q, int* __restrict__ flag) {
  __shared__ int cnt;
  if (threadIdx.x == 0) cnt = 0;
  __syncthreads();
  const int k = threadIdx.x * 16384 + 128;
  const u16 u = q[2 * k];
  const int e = (u >> 7) & 0xFF;
  if (e >= 96 && e <= 143) atomicAdd(&cnt, 1);
  __syncthreads();
  if (threadIdx.x == 0) *flag = (cnt < 128) ? 1 : 0;
}

// ---------- conversion helpers ----------
__device__ __forceinline__ short8 cvt8_f32(const float* s) {
  f32x4 a = *(const f32x4*)s;
  f32x4 b = *(const f32x4*)(s + 4);
  short8 o;
#pragma unroll
  for (int j = 0; j < 4; ++j) o[j] = (short)f2bf(a[j]);
#pragma unroll
  for (int j = 0; j < 4; ++j) o[4 + j] = (short)f2bf(b[j]);
  return o;
}

__global__ void cvt_tensor(const void* __restrict__ src, u16* __restrict__ dst,
                           int n8, const int* __restrict__ flag) {
  const bool isf32 = (*flag != 0);
  int i = blockIdx.x * blockDim.x + threadIdx.x;
  const int stride = gridDim.x * blockDim.x;
  if (isf32) {
    const float* s = (const float*)src;
    for (; i < n8; i += stride) *(short8*)(dst + i * 8) = cvt8_f32(s + i * 8);
  } else {
    const short8* s = (const short8*)src;
    for (; i < n8; i += stride) *(short8*)(dst + i * 8) = s[i];
  }
}

__global__ void cvt_w4(const void* s0, const void* s1, const void* s2, const void* s3,
                       u16* __restrict__ dst, const int* __restrict__ flag) {
  const bool isf32 = (*flag != 0);
  int i = blockIdx.x * blockDim.x + threadIdx.x;
  const int stride = gridDim.x * blockDim.x;
  for (; i < (1 << 19); i += stride) {
    const int seg = i >> 17, off = i & ((1 << 17) - 1);
    const void* s = (seg == 0) ? s0 : (seg == 1) ? s1 : (seg == 2) ? s2 : s3;
    u16* d = dst + ((long)seg << 20) + (long)off * 8;
    if (isf32) *(short8*)d = cvt8_f32((const float*)s + off * 8);
    else *(short8*)d = *((const short8*)s + off);
  }
}

__global__ void cvt_b4(const void* s0, const void* s1, const void* s2, const void* s3,
                       u16* __restrict__ dst, const int* __restrict__ flag) {
  const bool isf32 = (*flag != 0);
  int i = blockIdx.x * blockDim.x + threadIdx.x;
  if (i >= 512) return;
  const int seg = i >> 7, off = i & 127;
  const void* s = (seg == 0) ? s0 : (seg == 1) ? s1 : (seg == 2) ? s2 : s3;
  u16* d = dst + seg * 1024 + off * 8;
  if (isf32) *(short8*)d = cvt8_f32((const float*)s + off * 8);
  else *(short8*)d = *((const short8*)s + off);
}

// =====================================================================
// GEMM: C[M][N] = A[M][K] * W[N][K]^T + bias[N]  [m97 structure, unchanged]
// =====================================================================
template <int MODE>
__global__ __launch_bounds__(256, 2) void gemm_bt(
    const u16* __restrict__ A, const u16* __restrict__ W,
    const u16* __restrict__ bias, void* __restrict__ Cv,
    const int* __restrict__ flag, int M, int N, int K) {
  __shared__ __align__(16) u16 As[128 * 32];
  __shared__ __align__(16) u16 Bs[128 * 32];
  const int tid = threadIdx.x;
  const int lane = tid & 63;
  const int wv = tid >> 6;
  const int wr = wv >> 1, wc = wv & 1;
  const bool isf32 = (MODE == 0) && (*flag != 0);

  const int nwg = gridDim.x;
  const int cpx = nwg >> 3;
  const int bid = (blockIdx.x % 8) * cpx + (blockIdx.x >> 3);

  const int tiles_n = N >> 7;
  const int tm = bid / tiles_n, tn = bid % tiles_n;
  const int m0 = tm << 7, n0 = tn << 7;

  f32x4 acc[4][4];
#pragma unroll
  for (int i = 0; i < 4; ++i)
#pragma unroll
    for (int j = 0; j < 4; ++j)
#pragma unroll
      for (int r = 0; r < 4; ++r) acc[i][j][r] = 0.f;

  const int srow = tid >> 2;
  const int skk = (tid & 3) * 8;
  const u16* a0 = A + (long)(m0 + srow) * K + skk;
  const u16* a1 = A + (long)(m0 + 64 + srow) * K + skk;
  const u16* b0 = W + (long)(n0 + srow) * K + skk;
  const u16* b1 = W + (long)(n0 + 64 + srow) * K + skk;
  u16* lA0 = &As[tid * 8];
  u16* lA1 = &As[(256 + tid) * 8];
  u16* lB0 = &Bs[tid * 8];
  u16* lB1 = &Bs[(256 + tid) * 8];

  const int rk = 8 * (lane >> 4);
  const int rrow = lane & 15;
  const int r0 = (lane >> 4) * 4;

  for (int k0 = 0; k0 < K; k0 += 32) {
    GLOAD16(a0 + k0, lA0);
    GLOAD16(a1 + k0, lA1);
    GLOAD16(b0 + k0, lB0);
    GLOAD16(b1 + k0, lB1);
    asm volatile("s_waitcnt vmcnt(0)" ::: "memory");
    __syncthreads();
    short8 af[4], bf[4];
#pragma unroll
    for (int mi = 0; mi < 4; ++mi)
      af[mi] = *(const short8*)&As[(wr * 64 + mi * 16 + rrow) * 32 + rk];
#pragma unroll
    for (int ni = 0; ni < 4; ++ni)
      bf[ni] = *(const short8*)&Bs[(wc * 64 + ni * 16 + rrow) * 32 + rk];
#pragma unroll
    for (int mi = 0; mi < 4; ++mi)
#pragma unroll
      for (int ni = 0; ni < 4; ++ni)
        acc[mi][ni] = MFMA(af[mi], bf[ni], acc[mi][ni]);
    __syncthreads();
  }

#pragma unroll
  for (int ni = 0; ni < 4; ++ni) {
    const int col = n0 + wc * 64 + ni * 16 + rrow;
    const float bv = bf2f(bias[col]);
#pragma unroll
    for (int mi = 0; mi < 4; ++mi) {
#pragma unroll
      for (int r = 0; r < 4; ++r) {
        const int row = m0 + wr * 64 + mi * 16 + r0 + r;
        const float v = acc[mi][ni][r] + bv;
        if (MODE == 0) {
          const long idx = (long)row * N + col;
          if (isf32) ((float*)Cv)[idx] = v;
          else ((u16*)Cv)[idx] = f2bf(v);
        } else if (MODE == 1) {
          const int b = row >> 11, s = row & 2047, h = col >> 6, dh = col & 63;
          ((u16*)Cv)[(((long)(b * NH + h) * SQ) + s) * DH + dh] = f2bf(v);
        } else {
          const int b = row >> 11, s = row & 2047, h = col >> 6, dh = col & 63;
          ((u16*)Cv)[(((long)(b * NH + h) * DH) + dh) * SQ + s] = f2bf(v);
        }
      }
    }
  }
}

// =====================================================================
// Flash attention, swapped-QK^T (T12 structure):
//   S^T = mfma(K, Q)  => lane holds q-col = lane&15, kv = 16f + 4g + r
//   softmax: in-register tree + 2 shfl_xor (16,32); stats scalar per q-row
//   P: v_cvt_pk_bf16_f32 pairs (kv-consecutive) -> ds_write_b64 -> LDS
//   PV: A = P rows (q), B = V^T rows (dh)  [unchanged layout]
// q,k in [BH][S][64], vT in [BH][64][S], out ctx [B][S][H][64]
// grid (S/128, BH), 256 threads = 4 waves, each wave 32 q-rows, KVBLK=64
// =====================================================================
#define LSTR 72
#define SM_C 0.18033688011112043f  /* 0.125 * log2(e): scale folded into log2 domain */

__global__ __launch_bounds__(256, 2) void attn_kernel(
    const u16* __restrict__ q, const u16* __restrict__ k,
    const u16* __restrict__ vT, const int* __restrict__ mask,
    u16* __restrict__ ctx) {
  __shared__ __align__(16) u16 Ks[64 * LSTR];
  __shared__ __align__(16) u16 Vs[64 * LSTR];
  __shared__ __align__(16) u16 Ps[4][32 * LSTR];
  __shared__ __align__(16) float Msf[64];

  const int tid = threadIdx.x, lane = tid & 63, wv = tid >> 6;
  const int bh = blockIdx.y, b = bh >> 4, h = bh & 15;
  const int q0 = blockIdx.x * 128 + wv * 32;
  const u16* qb = q + (long)bh * SQ * DH;
  const u16* kb = k + (long)bh * SQ * DH;
  const u16* vb = vT + (long)bh * DH * SQ;
  const int g1 = lane >> 4;           // k-group 0..3
  const int rq = lane & 15;           // q-col / frag row
  const int rk = 8 * g1;              // k offset within 32-block
  const int r0 = 4 * g1;              // C-row base (accumulator space)

  // Q fragments (B-operand): lane holds Q[qrow = rq][dh = ks*32 + rk + j]
  short8 aq[2][2];
#pragma unroll
  for (int m = 0; m < 2; ++m)
#pragma unroll
    for (int ks = 0; ks < 2; ++ks)
      aq[m][ks] = *(const short8*)&qb[(long)(q0 + m * 16 + rq) * DH + ks * 32 + rk];

  f32x4 oacc[2][4];
  float mrow[2], lrow[2];
#pragma unroll
  for (int m = 0; m < 2; ++m) {
    mrow[m] = -1.0e9f;
    lrow[m] = 0.f;
#pragma unroll
    for (int nf = 0; nf < 4; ++nf)
#pragma unroll
      for (int r = 0; r < 4; ++r) oacc[m][nf][r] = 0.f;
  }

  const int stg_r = tid >> 3;
  const int stg_c = (tid & 7) * 8;

  for (int t0 = 0; t0 < SQ; t0 += 64) {
    // global -> regs
    const short8 kv0 = *(const short8*)&kb[(long)(t0 + stg_r) * DH + stg_c];
    const short8 kv1 = *(const short8*)&kb[(long)(t0 + 32 + stg_r) * DH + stg_c];
    const short8 vv0 = *(const short8*)&vb[(long)stg_r * SQ + t0 + stg_c];
    const short8 vv1 = *(const short8*)&vb[(long)(32 + stg_r) * SQ + t0 + stg_c];
    float mv = 0.f;
    if (tid < 64) mv = (mask[b * SQ + t0 + tid] != 0) ? 0.f : -1.0e9f;

    __syncthreads();  // prior iteration's LDS reads complete before overwrite
    *(short8*)&Ks[stg_r * LSTR + stg_c] = kv0;
    *(short8*)&Ks[(32 + stg_r) * LSTR + stg_c] = kv1;
    *(short8*)&Vs[stg_r * LSTR + stg_c] = vv0;
    *(short8*)&Vs[(32 + stg_r) * LSTR + stg_c] = vv1;
    if (tid < 64) Msf[tid] = mv;
    __syncthreads();  // staging visible

    // K fragments (A-operand): lane holds K[kv = f*16+rq][dh = ks*32+rk+j]
    short8 kf[4][2];
#pragma unroll
    for (int f = 0; f < 4; ++f)
#pragma unroll
      for (int ks = 0; ks < 2; ++ks)
        kf[f][ks] = *(const short8*)&Ks[(f * 16 + rq) * LSTR + ks * 32 + rk];
    // mask offsets for this lane's kv rows (kv = f*16 + 4*g1 + r)
    f32x4 mo[4];
#pragma unroll
    for (int f = 0; f < 4; ++f) mo[f] = *(const f32x4*)&Msf[f * 16 + 4 * g1];

    // ---- S^T = K Q^T : sacc[m][f], lane q-col = rq, kv = f*16+4g1+r ----
    f32x4 sacc[2][4];
#pragma unroll
    for (int m = 0; m < 2; ++m)
#pragma unroll
      for (int f = 0; f < 4; ++f)
#pragma unroll
        for (int r = 0; r < 4; ++r) sacc[m][f][r] = 0.f;
#pragma unroll
    for (int ks = 0; ks < 2; ++ks)
#pragma unroll
      for (int f = 0; f < 4; ++f)
#pragma unroll
        for (int m = 0; m < 2; ++m)
          sacc[m][f] = MFMA(kf[f][ks], aq[m][ks], sacc[m][f]);

    // fused mask + scale + log2e: s'' = s*C + moff   (1 fma per score)
#pragma unroll
    for (int m = 0; m < 2; ++m)
#pragma unroll
      for (int f = 0; f < 4; ++f)
#pragma unroll
        for (int r = 0; r < 4; ++r)
          sacc[m][f][r] = __builtin_fmaf(sacc[m][f][r], SM_C, mo[f][r]);

    // ---- online softmax (log2 domain), per q-row owned lane-locally ----
#pragma unroll
    for (int m = 0; m < 2; ++m) {
      // max tree over 16 in-register scores
      f32x4 t4;
#pragma unroll
      for (int r = 0; r < 4; ++r)
        t4[r] = fmaxf(fmaxf(sacc[m][0][r], sacc[m][1][r]),
                      fmaxf(sacc[m][2][r], sacc[m][3][r]));
      float vmax = fmaxf(fmaxf(t4[0], t4[1]), fmaxf(t4[2], t4[3]));
      vmax = fmaxf(vmax, __shfl_xor(vmax, 16));
      vmax = fmaxf(vmax, __shfl_xor(vmax, 32));

      const float mnew = fmaxf(mrow[m], vmax);
      const float sc = EXP2(mrow[m] - mnew);
      mrow[m] = mnew;

      // exp + sum tree
#pragma unroll
      for (int f = 0; f < 4; ++f)
#pragma unroll
        for (int r = 0; r < 4; ++r)
          sacc[m][f][r] = EXP2(sacc[m][f][r] - mnew);
      f32x4 s4;
#pragma unroll
      for (int r = 0; r < 4; ++r)
        s4[r] = (sacc[m][0][r] + sacc[m][1][r]) + (sacc[m][2][r] + sacc[m][3][r]);
      float tsum = (s4[0] + s4[1]) + (s4[2] + s4[3]);
      tsum += __shfl_xor(tsum, 16);
      tsum += __shfl_xor(tsum, 32);
      lrow[m] = lrow[m] * sc + tsum;

      // redistribute rescale factor to accumulator rows (q = m*16 + 4g1 + r)
      f32x4 scr;
#pragma unroll
      for (int r = 0; r < 4; ++r) scr[r] = __shfl(sc, 4 * g1 + r);
#pragma unroll
      for (int nf = 0; nf < 4; ++nf)
#pragma unroll
        for (int r = 0; r < 4; ++r) oacc[m][nf][r] *= scr[r];

      // P -> LDS: kv-consecutive pairs, packed bf16, b64 store
#pragma unroll
      for (int f = 0; f < 4; ++f) {
        u32x2 w;
        w[0] = CVTPK(sacc[m][f][0], sacc[m][f][1]);
        w[1] = CVTPK(sacc[m][f][2], sacc[m][f][3]);
        *(u32x2*)&Ps[wv][(m * 16 + rq) * LSTR + f * 16 + 4 * g1] = w;
      }
    }

    __syncthreads();  // Ps visible (wave-private but keep hard sync for safety)

    // ---- O += P V : A = P rows (q), B = V^T rows (dh) ----
#pragma unroll
    for (int ks2 = 0; ks2 < 2; ++ks2) {
      short8 pa[2];
#pragma unroll
      for (int m = 0; m < 2; ++m)
        pa[m] = *(const short8*)&Ps[wv][(m * 16 + rq) * LSTR + ks2 * 32 + rk];
#pragma unroll
      for (int nf = 0; nf < 4; ++nf) {
        const short8 bvv = *(const short8*)&Vs[(nf * 16 + rq) * LSTR + ks2 * 32 + rk];
#pragma unroll
        for (int m = 0; m < 2; ++m)
          oacc[m][nf] = MFMA(pa[m], bvv, oacc[m][nf]);
      }
    }
  }

  // epilogue: ctx[b][s][h][dh]; stats live in lane rq-space -> shfl to row-space
#pragma unroll
  for (int m = 0; m < 2; ++m) {
    const float inv = 1.0f / lrow[m];
    f32x4 invr;
#pragma unroll
    for (int r = 0; r < 4; ++r) invr[r] = __shfl(inv, 4 * g1 + r);
#pragma unroll
    for (int nf = 0; nf < 4; ++nf)
#pragma unroll
      for (int r = 0; r < 4; ++r) {
        const int s = q0 + m * 16 + r0 + r;
        const int dh = nf * 16 + rq;
        ctx[(((long)(b * SQ + s)) * NH + h) * DH + dh] = f2bf(oacc[m][nf][r] * invr[r]);
      }
  }
}

// =====================================================================
extern "C" void kernel_launch(void* const* d_in, const int* in_sizes, int n_in,
                              void* d_out, int out_size, void* d_ws, size_t ws_size,
                              hipStream_t stream) {
  const void* query = d_in[0];
  const int* mask = (const int*)d_in[1];
  const void* Wq = d_in[2];
  const void* bq = d_in[3];
  const void* Wk = d_in[4];
  const void* bk = d_in[5];
  const void* Wv = d_in[6];
  const void* bv = d_in[7];
  const void* Wo = d_in[8];
  const void* bo = d_in[9];

  // ws layout (bytes)
  char* w = (char*)d_ws;
  int* flag = (int*)w;
  u16* qc = (u16*)(w + 256);                 // 8.39M u16
  u16* Wc = qc + (long)8388608;              // 4 x 1M u16
  u16* bc = Wc + (long)4 * 1048576;          // 4 x 1024 u16
  u16* qb = bc + 4096;                       // heads Q
  u16* kb = qb + (long)8388608;              // heads K
  u16* vT = kb + (long)8388608;              // V transposed
  u16* ctx = vT + (long)8388608;             // attention output

  dim3 blk(256);

  detect_dtype<<<1, 256, 0, stream>>>((const u16*)query, flag);
  cvt_tensor<<<2048, 256, 0, stream>>>(query, qc, 8388608 / 8, flag);
  cvt_w4<<<2048, 256, 0, stream>>>(Wq, Wk, Wv, Wo, Wc, flag);
  cvt_b4<<<2, 256, 0, stream>>>(bq, bk, bv, bo, bc, flag);

  const int M = 4 * SQ;  // 8192
  dim3 gemm_grid((M / 128) * (DMODEL / 128));  // 512

  gemm_bt<1><<<gemm_grid, blk, 0, stream>>>(qc, Wc, bc, (void*)qb, flag, M, DMODEL, DMODEL);
  gemm_bt<1><<<gemm_grid, blk, 0, stream>>>(qc, Wc + 1048576, bc + 1024, (void*)kb, flag, M, DMODEL, DMODEL);
  gemm_bt<2><<<gemm_grid, blk, 0, stream>>>(qc, Wc + 2 * 1048576, bc + 2048, (void*)vT, flag, M, DMODEL, DMODEL);

  dim3 attn_grid(SQ / 128, 64);
  attn_kernel<<<attn_grid, blk, 0, stream>>>(qb, kb, vT, mask, ctx);

  gemm_bt<0><<<gemm_grid, blk, 0, stream>>>(ctx, Wc + 3 * 1048576, bc + 3072, d_out, flag, M, DMODEL, DMODEL);
}